// Round 11
// baseline (189.480 us; speedup 1.0000x reference)
//
#include <hip/hip_runtime.h>
#include <math.h>

#define N_NODES 50000
#define N_EDGES 800000
#define HEADS 4
#define OUT_C 64
#define HC 256            // HEADS*OUT_C
#define NEG_SLOPE 0.2f
#define N_CHUNKS ((N_NODES + 255) / 256)   // 196
#define WT_BLOCKS 64                        // W transpose blocks
#define HIST_BLOCKS (N_EDGES / 256)         // 3125

typedef __attribute__((ext_vector_type(8))) short bf16x8;
typedef __attribute__((ext_vector_type(4))) float f32x4;

// float -> bf16 (round-to-nearest-even); inputs are finite
__device__ inline unsigned short f2bf(float f) {
    unsigned u = __float_as_uint(f);
    return (unsigned short)((u + 0x7FFFu + ((u >> 16) & 1u)) >> 16);
}
__device__ inline float bf2f(unsigned short h) {
    return __uint_as_float(((unsigned)h) << 16);
}

// sum across the 16 lanes of a DPP row (head group) via row_ror adds: pure VALU
__device__ inline float rowsum16(float p) {
    int y;
    y = __builtin_amdgcn_update_dpp(0, __float_as_int(p), 0x121, 0xF, 0xF, false);
    p += __int_as_float(y);
    y = __builtin_amdgcn_update_dpp(0, __float_as_int(p), 0x122, 0xF, 0xF, false);
    p += __int_as_float(y);
    y = __builtin_amdgcn_update_dpp(0, __float_as_int(p), 0x124, 0xF, 0xF, false);
    p += __int_as_float(y);
    y = __builtin_amdgcn_update_dpp(0, __float_as_int(p), 0x128, 0xF, 0xF, false);
    p += __int_as_float(y);
    return p;
}

// ---- prep: blocks [0,64) transpose+convert W -> Wt[c][k] bf16; rest histogram dst ----
__global__ void k_prep(const float* __restrict__ W, unsigned short* __restrict__ Wt,
                       const int* __restrict__ dst, int* __restrict__ cnt) {
    int b = blockIdx.x, t = threadIdx.x;
    if (b < WT_BLOCKS) {
        int idx = b * 256 + t;              // 0..16383
        int c = idx >> 6, k = idx & 63;
        Wt[idx] = f2bf(W[(size_t)k * HC + c]);
        return;
    }
    int e = (b - WT_BLOCKS) * 256 + t;      // exactly covers N_EDGES
    atomicAdd(&cnt[dst[e]], 1);
}

// ---- MFMA GEMM: xl = bf16(x @ W). One block = 16 node-rows; wave w covers
// col-tiles c0 = w*16 + i*64. A-frag: lane l = row (l&15), k = (l>>4)*8+j.
// B-frag from Wt[c][k]: col = l&15, same k mapping. D: col = l&15, row = (l>>4)*4+j.
__global__ __launch_bounds__(256) void k_gemm(const float* __restrict__ x,
                                              const unsigned short* __restrict__ Wt,
                                              unsigned short* __restrict__ xlh) {
    int wv = threadIdx.x >> 6, l = threadIdx.x & 63;
    int row0 = blockIdx.x * 16;
    int r = l & 15, kg = l >> 4, ko = kg * 8;
    const float* xrow = x + (size_t)(row0 + r) * OUT_C;
    f32x4 a0 = *(const f32x4*)(xrow + ko);
    f32x4 a1 = *(const f32x4*)(xrow + ko + 4);
    f32x4 a2 = *(const f32x4*)(xrow + 32 + ko);
    f32x4 a3 = *(const f32x4*)(xrow + 32 + ko + 4);
    bf16x8 A0, A1;
    #pragma unroll
    for (int j = 0; j < 4; ++j) {
        A0[j]     = (short)f2bf(a0[j]);
        A0[j + 4] = (short)f2bf(a1[j]);
        A1[j]     = (short)f2bf(a2[j]);
        A1[j + 4] = (short)f2bf(a3[j]);
    }
    int drow = kg * 4;
    #pragma unroll
    for (int i = 0; i < 4; ++i) {
        int c0 = wv * 16 + i * 64;
        const unsigned short* wp = Wt + (size_t)(c0 + r) * OUT_C + ko;
        bf16x8 B0 = *(const bf16x8*)(wp);
        bf16x8 B1 = *(const bf16x8*)(wp + 32);
        f32x4 acc = {0.f, 0.f, 0.f, 0.f};
        acc = __builtin_amdgcn_mfma_f32_16x16x32_bf16(A0, B0, acc, 0, 0, 0);
        acc = __builtin_amdgcn_mfma_f32_16x16x32_bf16(A1, B1, acc, 0, 0, 0);
        #pragma unroll
        for (int j = 0; j < 4; ++j)
            xlh[(size_t)(row0 + drow + j) * HC + c0 + r] = f2bf(acc[j]);
    }
}

// ---- fused scan: per-chunk local exclusive scan + last-block scans chunk totals ----
__global__ void k_scan(const int* __restrict__ cnt, int* __restrict__ rowL,
                       int* __restrict__ tops, int* __restrict__ topsS,
                       int* __restrict__ done) {
    __shared__ int wsum[4];
    __shared__ int wsum2[4];
    __shared__ int lastflag;
    int t = threadIdx.x, b = blockIdx.x;
    int idx = b * 256 + t;
    int v = (idx < N_NODES) ? cnt[idx] : 0;
    int lane = t & 63, w = t >> 6;
    int x = v;
    #pragma unroll
    for (int off = 1; off < 64; off <<= 1) {
        int y = __shfl_up(x, off);
        if (lane >= off) x += y;
    }
    if (lane == 63) wsum[w] = x;
    __syncthreads();
    if (t == 0) {
        int s0 = wsum[0], s1 = wsum[1], s2 = wsum[2], s3 = wsum[3];
        wsum[0] = 0; wsum[1] = s0; wsum[2] = s0 + s1; wsum[3] = s0 + s1 + s2;
        tops[b] = s0 + s1 + s2 + s3;
    }
    __syncthreads();
    if (idx < N_NODES) rowL[idx] = x - v + wsum[w];
    // last block to arrive scans the chunk totals
    __threadfence();
    if (t == 0) lastflag = (atomicAdd(done, 1) == N_CHUNKS - 1);
    __syncthreads();
    if (!lastflag) return;
    __threadfence();
    int v2 = (t < N_CHUNKS) ? tops[t] : 0;
    int x2 = v2;
    #pragma unroll
    for (int off = 1; off < 64; off <<= 1) {
        int y = __shfl_up(x2, off);
        if (lane >= off) x2 += y;
    }
    if (lane == 63) wsum2[w] = x2;
    __syncthreads();
    if (t == 0) {
        int s0 = wsum2[0], s1 = wsum2[1], s2 = wsum2[2];
        wsum2[0] = 0; wsum2[1] = s0; wsum2[2] = s0 + s1; wsum2[3] = s0 + s1 + s2;
    }
    __syncthreads();
    topsS[t] = x2 - v2 + wsum2[w];
}

// scatter src ids into dst-sorted order; cnt counts back down (acts as cursor);
// tail threads write 16 sentinel zeros so k_node's prefetch can run unclamped
__global__ void k_fill(const int* __restrict__ src, const int* __restrict__ dst,
                       int* __restrict__ cnt, const int* __restrict__ rowL,
                       const int* __restrict__ topsS, int* __restrict__ ssorted) {
    int e = blockIdx.x * blockDim.x + threadIdx.x;
    if (e >= N_EDGES) {
        if (e < N_EDGES + 16) ssorted[e] = 0;
        return;
    }
    int d = dst[e];
    int slot = atomicAdd(&cnt[d], -1) - 1;          // unique in [0, deg)
    int pos = rowL[d] + topsS[d >> 8] + slot;
    ssorted[pos] = src[e];
}

// ---------------- fused softmax + aggregate: one WAVE per node ----------------
// lane owns channels [4*lane, 4*lane+4); head = lane>>4 (16 lanes per head).
// bf16 rows (512 B); no max-subtraction (shift-invariant, |score| O(10)).
__global__ __launch_bounds__(256) void k_node(
    const unsigned short* __restrict__ xlh, const int* __restrict__ rowL,
    const int* __restrict__ topsS, const int* __restrict__ ssorted,
    const float* __restrict__ att, const float* __restrict__ bias,
    float* __restrict__ out) {
    int w = threadIdx.x >> 6;
    int lane = threadIdx.x & 63;
    int n = blockIdx.x * 4 + w;                    // grid = 12500 exact
    int start = rowL[n] + topsS[n >> 8];
    int end = (n == N_NODES - 1) ? N_EDGES : (rowL[n + 1] + topsS[(n + 1) >> 8]);
    start = __builtin_amdgcn_readfirstlane(start); // scalar edge-list walk
    end   = __builtin_amdgcn_readfirstlane(end);
    int ne = end - start;
    const int* sp = ssorted + start;
    int c4 = lane << 2;
    const unsigned short* xp = xlh + c4;
    ushort4 xq = *(const ushort4*)(xp + (size_t)n * HC);
    float4 xn = make_float4(bf2f(xq.x), bf2f(xq.y), bf2f(xq.z), bf2f(xq.w));
    const float4 at = *(const float4*)(att + c4);
    float4 acc = make_float4(0.f, 0.f, 0.f, 0.f);
    float den = 0.0f;

#define EDGE(vq) {                                                        \
        float4 vc = make_float4(bf2f(vq.x), bf2f(vq.y),                   \
                                bf2f(vq.z), bf2f(vq.w));                  \
        float f, p;                                                       \
        f = xn.x + vc.x; f = f > 0.f ? f : NEG_SLOPE * f; p  = f * at.x;  \
        f = xn.y + vc.y; f = f > 0.f ? f : NEG_SLOPE * f; p += f * at.y;  \
        f = xn.z + vc.z; f = f > 0.f ? f : NEG_SLOPE * f; p += f * at.z;  \
        f = xn.w + vc.w; f = f > 0.f ? f : NEG_SLOPE * f; p += f * at.w;  \
        p = rowsum16(p);                                                  \
        float ex = __expf(p);                                             \
        den += ex;                                                        \
        acc.x += ex * vc.x; acc.y += ex * vc.y;                           \
        acc.z += ex * vc.z; acc.w += ex * vc.w; }

    if (ne > 0) {
        // depth-2 pipeline; prefetch indices/rows run into the 16-int sentinel pad
        int sa = sp[0];
        int sb = sp[1];
        ushort4 va = *(const ushort4*)(xp + (size_t)sa * HC);
        ushort4 vb = *(const ushort4*)(xp + (size_t)sb * HC);
        sa = sp[2];
        sb = sp[3];
        int i = 0;
        for (; i + 1 < ne; i += 2) {
            ushort4 v0 = va, v1 = vb;
            va = *(const ushort4*)(xp + (size_t)sa * HC);
            vb = *(const ushort4*)(xp + (size_t)sb * HC);
            sa = sp[i + 4];
            sb = sp[i + 5];
            EDGE(v0);
            EDGE(v1);
        }
        if (i < ne) EDGE(va);
    }
#undef EDGE

    float r = 1.0f / (den > 0.0f ? den : 1.0f);
    const float4 b4 = *(const float4*)(bias + c4);
    float4 o;
    o.x = fmaxf(acc.x * r + b4.x, 0.0f);
    o.y = fmaxf(acc.y * r + b4.y, 0.0f);
    o.z = fmaxf(acc.z * r + b4.z, 0.0f);
    o.w = fmaxf(acc.w * r + b4.w, 0.0f);
    *(float4*)(out + (size_t)n * HC + c4) = o;
}

extern "C" void kernel_launch(void* const* d_in, const int* in_sizes, int n_in,
                              void* d_out, int out_size, void* d_ws, size_t ws_size,
                              hipStream_t stream) {
    const float* x    = (const float*)d_in[0];
    const int*   edge = (const int*)d_in[1];     // [2, E] int32
    const float* W    = (const float*)d_in[2];
    const float* att  = (const float*)d_in[3];
    const float* bias = (const float*)d_in[4];
    float* out = (float*)d_out;

    const int* src = edge;
    const int* dst = edge + N_EDGES;

    // workspace layout (16B-aligned)
    char* ws = (char*)d_ws;
    unsigned short* xlh = (unsigned short*)ws;          // 25,600,000 B (bf16 xl)
    int* cnt     = (int*)(ws + 25600000);               //   200,000 B
    int* done    = (int*)(ws + 25800000);               //        64 B (memset w/ cnt)
    int* rowL    = (int*)(ws + 25800064);               //   200,000 B
    int* ssorted = (int*)(ws + 26000064);               // 3,200,064 B (+16 pad ints)
    int* tops    = (int*)(ws + 29200192);               //     1,024 B
    int* topsS   = (int*)(ws + 29201216);               //     1,024 B
    unsigned short* Wt = (unsigned short*)(ws + 29202240); // 32,768 B (bf16 W^T [256][64])
    // total ~29.24 MB

    hipMemsetAsync(cnt, 0, 200064, stream);  // cnt + done
    k_prep<<<WT_BLOCKS + HIST_BLOCKS, 256, 0, stream>>>(W, Wt, dst, cnt);
    k_gemm<<<N_NODES / 16, 256, 0, stream>>>(x, Wt, xlh);
    k_scan<<<N_CHUNKS, 256, 0, stream>>>(cnt, rowL, tops, topsS, done);
    k_fill<<<(N_EDGES + 16 + 255) / 256, 256, 0, stream>>>(src, dst, cnt, rowL, topsS, ssorted);
    k_node<<<N_NODES / 4, 256, 0, stream>>>(xlh, rowL, topsS, ssorted, att, bias, out);
}

// Round 12
// 132.124 us; speedup vs baseline: 1.4341x; 1.4341x over previous
//
#include <hip/hip_runtime.h>
#include <math.h>

#define N_NODES 50000
#define N_EDGES 800000
#define HEADS 4
#define OUT_C 64
#define HC 256            // HEADS*OUT_C
#define NEG_SLOPE 0.2f
#define NBUCKET 196       // ceil(N_NODES/256)
#define CHUNK 1000
#define NBLK 800          // NBLK*CHUNK == N_EDGES exactly
#define WT_BLOCKS 64
#define GEMM_BLOCKS (N_NODES / 16)   // 3125

typedef __attribute__((ext_vector_type(8))) short bf16x8;
typedef __attribute__((ext_vector_type(4))) float f32x4;

// float -> bf16 (round-to-nearest-even); inputs are finite
__device__ inline unsigned short f2bf(float f) {
    unsigned u = __float_as_uint(f);
    return (unsigned short)((u + 0x7FFFu + ((u >> 16) & 1u)) >> 16);
}
__device__ inline float bf2f(unsigned short h) {
    return __uint_as_float(((unsigned)h) << 16);
}

// sum across the 16 lanes of a DPP row (head group) via row_ror adds: pure VALU
__device__ inline float rowsum16(float p) {
    int y;
    y = __builtin_amdgcn_update_dpp(0, __float_as_int(p), 0x121, 0xF, 0xF, false);
    p += __int_as_float(y);
    y = __builtin_amdgcn_update_dpp(0, __float_as_int(p), 0x122, 0xF, 0xF, false);
    p += __int_as_float(y);
    y = __builtin_amdgcn_update_dpp(0, __float_as_int(p), 0x124, 0xF, 0xF, false);
    p += __int_as_float(y);
    y = __builtin_amdgcn_update_dpp(0, __float_as_int(p), 0x128, 0xF, 0xF, false);
    p += __int_as_float(y);
    return p;
}

// ---- K1: blocks [0,NBLK) LDS-histogram dst>>8 -> M[bin][blk];
//          blocks [NBLK,NBLK+64) transpose W -> Wt bf16 (one also zeroes done)
__global__ void k_hist1(const int* __restrict__ dst, int* __restrict__ M,
                        const float* __restrict__ W, unsigned short* __restrict__ Wt,
                        int* __restrict__ done) {
    int b = blockIdx.x, t = threadIdx.x;
    if (b >= NBLK) {
        if (b == NBLK && t == 0) *done = 0;
        int idx = (b - NBLK) * 256 + t;     // 0..16383
        int c = idx >> 6, k = idx & 63;
        Wt[idx] = f2bf(W[(size_t)k * HC + c]);
        return;
    }
    __shared__ int h[NBUCKET];
    if (t < NBUCKET) h[t] = 0;
    __syncthreads();
    int base = b * CHUNK;
    for (int i = base + t; i < base + CHUNK; i += 256)
        atomicAdd(&h[dst[i] >> 8], 1);
    __syncthreads();
    if (t < NBUCKET) M[(size_t)t * NBLK + b] = h[t];
}

// ---- K2: 196 blocks; block b exclusive-scans M[b][0..799] in place;
//          last block scans bucket totals -> coarseBase, writes sentinels
__global__ void k_scan2(int* __restrict__ M, int* __restrict__ coarse,
                        int* __restrict__ coarseBase, int* __restrict__ rowL,
                        int* __restrict__ ssorted, int* __restrict__ done) {
    __shared__ int wsum[4];
    __shared__ int carry_s, tot_s, lastflag;
    int b = blockIdx.x, t = threadIdx.x;
    int lane = t & 63, w = t >> 6;
    if (t == 0) carry_s = 0;
    __syncthreads();
    int* Mrow = M + (size_t)b * NBLK;
    for (int c0 = 0; c0 < NBLK; c0 += 256) {
        int idx = c0 + t;
        int v = (idx < NBLK) ? Mrow[idx] : 0;
        int x = v;
        #pragma unroll
        for (int off = 1; off < 64; off <<= 1) {
            int y = __shfl_up(x, off);
            if (lane >= off) x += y;
        }
        if (lane == 63) wsum[w] = x;
        __syncthreads();
        if (t == 0) {
            int s0 = wsum[0], s1 = wsum[1], s2 = wsum[2], s3 = wsum[3];
            wsum[0] = 0; wsum[1] = s0; wsum[2] = s0 + s1; wsum[3] = s0 + s1 + s2;
            tot_s = s0 + s1 + s2 + s3;
        }
        __syncthreads();
        int excl = x - v + wsum[w] + carry_s;
        if (idx < NBLK) Mrow[idx] = excl;
        __syncthreads();
        if (t == 0) carry_s += tot_s;
        __syncthreads();
    }
    if (t == 0) coarse[b] = carry_s;
    __threadfence();
    if (t == 0) lastflag = (atomicAdd(done, 1) == NBUCKET - 1);
    __syncthreads();
    if (!lastflag) return;
    if (t == 0) *done = 0;                  // reset for next replay
    __threadfence();
    int v = (t < NBUCKET) ? coarse[t] : 0;
    int x = v;
    #pragma unroll
    for (int off = 1; off < 64; off <<= 1) {
        int y = __shfl_up(x, off);
        if (lane >= off) x += y;
    }
    if (lane == 63) wsum[w] = x;
    __syncthreads();
    if (t == 0) {
        int s0 = wsum[0], s1 = wsum[1], s2 = wsum[2];
        wsum[0] = 0; wsum[1] = s0; wsum[2] = s0 + s1; wsum[3] = s0 + s1 + s2;
    }
    __syncthreads();
    int excl = x - v + wsum[w];
    if (t < NBUCKET) coarseBase[t] = excl;
    if (t == NBUCKET - 1) coarseBase[NBUCKET] = excl + v;   // = N_EDGES
    if (t == 0) rowL[N_NODES] = N_EDGES;
    if (t < 16) ssorted[N_EDGES + t] = 0;   // sentinel pad for k_node prefetch
}

// ---- K3: blocks [0,NBLK) scatter (dst,src) into bucket-grouped tmp via LDS cursors;
//          blocks [NBLK,..) run the MFMA GEMM concurrently (independent work)
__global__ __launch_bounds__(256) void k_scatter_gemm(
    const int* __restrict__ src, const int* __restrict__ dst,
    const int* __restrict__ M, const int* __restrict__ coarseBase,
    int2* __restrict__ tmp,
    const float* __restrict__ x, const unsigned short* __restrict__ Wt,
    unsigned short* __restrict__ xlh) {
    int b = blockIdx.x, t = threadIdx.x;
    if (b < NBLK) {
        __shared__ int cur[NBUCKET];
        if (t < NBUCKET) cur[t] = coarseBase[t] + M[(size_t)t * NBLK + b];
        __syncthreads();
        int base = b * CHUNK;
        for (int i = base + t; i < base + CHUNK; i += 256) {
            int d = dst[i];
            int pos = atomicAdd(&cur[d >> 8], 1);
            tmp[pos] = make_int2(d, src[i]);
        }
        return;
    }
    // ---- MFMA GEMM: xl = bf16(x @ W); A: row=l&15, k=(l>>4)*8+j; D: col=l&15, row=(l>>4)*4+j
    int wv = t >> 6, l = t & 63;
    int row0 = (b - NBLK) * 16;
    int r = l & 15, kg = l >> 4, ko = kg * 8;
    const float* xrow = x + (size_t)(row0 + r) * OUT_C;
    f32x4 a0 = *(const f32x4*)(xrow + ko);
    f32x4 a1 = *(const f32x4*)(xrow + ko + 4);
    f32x4 a2 = *(const f32x4*)(xrow + 32 + ko);
    f32x4 a3 = *(const f32x4*)(xrow + 32 + ko + 4);
    bf16x8 A0, A1;
    #pragma unroll
    for (int j = 0; j < 4; ++j) {
        A0[j]     = (short)f2bf(a0[j]);
        A0[j + 4] = (short)f2bf(a1[j]);
        A1[j]     = (short)f2bf(a2[j]);
        A1[j + 4] = (short)f2bf(a3[j]);
    }
    int drow = kg * 4;
    #pragma unroll
    for (int i = 0; i < 4; ++i) {
        int c0 = wv * 16 + i * 64;
        const unsigned short* wp = Wt + (size_t)(c0 + r) * OUT_C + ko;
        bf16x8 B0 = *(const bf16x8*)(wp);
        bf16x8 B1 = *(const bf16x8*)(wp + 32);
        f32x4 acc = {0.f, 0.f, 0.f, 0.f};
        acc = __builtin_amdgcn_mfma_f32_16x16x32_bf16(A0, B0, acc, 0, 0, 0);
        acc = __builtin_amdgcn_mfma_f32_16x16x32_bf16(A1, B1, acc, 0, 0, 0);
        #pragma unroll
        for (int j = 0; j < 4; ++j)
            xlh[(size_t)(row0 + drow + j) * HC + c0 + r] = f2bf(acc[j]);
    }
}

// ---- K4: one block per bucket: LDS hist over local 256 nodes + LDS scan ->
//          rowL (global CSR starts) and LDS cursors -> ssorted. LDS atomics only.
__global__ void k_csr(const int2* __restrict__ tmp, const int* __restrict__ coarseBase,
                      int* __restrict__ rowL, int* __restrict__ ssorted) {
    __shared__ int h[256];
    __shared__ int cur[256];
    __shared__ int wsum[4];
    int b = blockIdx.x, t = threadIdx.x;
    int lane = t & 63, w = t >> 6;
    int s = coarseBase[b], e = coarseBase[b + 1];
    h[t] = 0;
    __syncthreads();
    for (int i = s + t; i < e; i += 256)
        atomicAdd(&h[tmp[i].x & 255], 1);
    __syncthreads();
    int v = h[t];
    int x = v;
    #pragma unroll
    for (int off = 1; off < 64; off <<= 1) {
        int y = __shfl_up(x, off);
        if (lane >= off) x += y;
    }
    if (lane == 63) wsum[w] = x;
    __syncthreads();
    if (t == 0) {
        int s0 = wsum[0], s1 = wsum[1], s2 = wsum[2];
        wsum[0] = 0; wsum[1] = s0; wsum[2] = s0 + s1; wsum[3] = s0 + s1 + s2;
    }
    __syncthreads();
    int excl = x - v + wsum[w];
    int n = b * 256 + t;
    if (n < N_NODES) rowL[n] = s + excl;
    cur[t] = s + excl;
    __syncthreads();
    for (int i = s + t; i < e; i += 256) {
        int2 p = tmp[i];
        int pos = atomicAdd(&cur[p.x & 255], 1);
        ssorted[pos] = p.y;
    }
}

// ---------------- fused softmax + aggregate: one WAVE per node ----------------
// lane owns channels [4*lane, 4*lane+4); head = lane>>4 (16 lanes per head).
// bf16 rows (512 B); no max-subtraction (shift-invariant, |score| O(10)).
__global__ __launch_bounds__(256) void k_node(
    const unsigned short* __restrict__ xlh, const int* __restrict__ rowL,
    const int* __restrict__ ssorted, const float* __restrict__ att,
    const float* __restrict__ bias, float* __restrict__ out) {
    int w = threadIdx.x >> 6;
    int lane = threadIdx.x & 63;
    int n = blockIdx.x * 4 + w;                    // grid = 12500 exact
    int start = __builtin_amdgcn_readfirstlane(rowL[n]);
    int end   = __builtin_amdgcn_readfirstlane(rowL[n + 1]);
    int ne = end - start;
    const int* sp = ssorted + start;
    int c4 = lane << 2;
    const unsigned short* xp = xlh + c4;
    ushort4 xq = *(const ushort4*)(xp + (size_t)n * HC);
    float4 xn = make_float4(bf2f(xq.x), bf2f(xq.y), bf2f(xq.z), bf2f(xq.w));
    const float4 at = *(const float4*)(att + c4);
    float4 acc = make_float4(0.f, 0.f, 0.f, 0.f);
    float den = 0.0f;

#define EDGE(vq) {                                                        \
        float4 vc = make_float4(bf2f(vq.x), bf2f(vq.y),                   \
                                bf2f(vq.z), bf2f(vq.w));                  \
        float f, p;                                                       \
        f = xn.x + vc.x; f = f > 0.f ? f : NEG_SLOPE * f; p  = f * at.x;  \
        f = xn.y + vc.y; f = f > 0.f ? f : NEG_SLOPE * f; p += f * at.y;  \
        f = xn.z + vc.z; f = f > 0.f ? f : NEG_SLOPE * f; p += f * at.z;  \
        f = xn.w + vc.w; f = f > 0.f ? f : NEG_SLOPE * f; p += f * at.w;  \
        p = rowsum16(p);                                                  \
        float ex = __expf(p);                                             \
        den += ex;                                                        \
        acc.x += ex * vc.x; acc.y += ex * vc.y;                           \
        acc.z += ex * vc.z; acc.w += ex * vc.w; }

    if (ne > 0) {
        // depth-2 pipeline; prefetch indices/rows run into the 16-int sentinel pad
        int sa = sp[0];
        int sb = sp[1];
        ushort4 va = *(const ushort4*)(xp + (size_t)sa * HC);
        ushort4 vb = *(const ushort4*)(xp + (size_t)sb * HC);
        sa = sp[2];
        sb = sp[3];
        int i = 0;
        for (; i + 1 < ne; i += 2) {
            ushort4 v0 = va, v1 = vb;
            va = *(const ushort4*)(xp + (size_t)sa * HC);
            vb = *(const ushort4*)(xp + (size_t)sb * HC);
            sa = sp[i + 4];
            sb = sp[i + 5];
            EDGE(v0);
            EDGE(v1);
        }
        if (i < ne) EDGE(va);
    }
#undef EDGE

    float r = 1.0f / (den > 0.0f ? den : 1.0f);
    const float4 b4 = *(const float4*)(bias + c4);
    float4 o;
    o.x = fmaxf(acc.x * r + b4.x, 0.0f);
    o.y = fmaxf(acc.y * r + b4.y, 0.0f);
    o.z = fmaxf(acc.z * r + b4.z, 0.0f);
    o.w = fmaxf(acc.w * r + b4.w, 0.0f);
    *(float4*)(out + (size_t)n * HC + c4) = o;
}

extern "C" void kernel_launch(void* const* d_in, const int* in_sizes, int n_in,
                              void* d_out, int out_size, void* d_ws, size_t ws_size,
                              hipStream_t stream) {
    const float* x    = (const float*)d_in[0];
    const int*   edge = (const int*)d_in[1];     // [2, E] int32
    const float* W    = (const float*)d_in[2];
    const float* att  = (const float*)d_in[3];
    const float* bias = (const float*)d_in[4];
    float* out = (float*)d_out;

    const int* src = edge;
    const int* dst = edge + N_EDGES;

    // workspace layout (8/16B-aligned)
    char* ws = (char*)d_ws;
    unsigned short* xlh = (unsigned short*)ws;            // 25,600,000 B
    unsigned short* Wt  = (unsigned short*)(ws + 25600000); //    32,768 B
    int* M          = (int*)(ws + 25632768);              //   627,200 B (196*800)
    int* coarse     = (int*)(ws + 26259968);              //       832 B
    int* coarseBase = (int*)(ws + 26260800);              //       832 B (197)
    int* done       = (int*)(ws + 26261632);              //        64 B
    int* rowL       = (int*)(ws + 26261696);              //   200,064 B (50001)
    int2* tmp       = (int2*)(ws + 26461760);             // 6,400,000 B
    int* ssorted    = (int*)(ws + 32861760);              // 3,200,064 B (+16 pad)
    // total ~36.1 MB

    k_hist1<<<NBLK + WT_BLOCKS, 256, 0, stream>>>(dst, M, W, Wt, done);
    k_scan2<<<NBUCKET, 256, 0, stream>>>(M, coarse, coarseBase, rowL, ssorted, done);
    k_scatter_gemm<<<NBLK + GEMM_BLOCKS, 256, 0, stream>>>(src, dst, M, coarseBase,
                                                           tmp, x, Wt, xlh);
    k_csr<<<NBUCKET, 256, 0, stream>>>(tmp, coarseBase, rowL, ssorted);
    k_node<<<N_NODES / 4, 256, 0, stream>>>(xlh, rowL, ssorted, att, bias, out);
}